// Round 3
// baseline (238491.504 us; speedup 1.0000x reference)
//
#include <hip/hip_runtime.h>
#include <stdint.h>

#define TSEQ 32768
#define HDIM 512
#define NWGL 32         // workgroups per layer
#define WGT  512        // threads per workgroup (8 waves)
#define DPW  16         // hidden dims per workgroup
#define POISON32 0x7FA57FA5u   // each u16 half is a bf16 NaN; finite h never produces it

typedef float f4 __attribute__((ext_vector_type(4)));

__device__ __forceinline__ float sigf(float x){ return 1.f/(1.f+__expf(-x)); }
__device__ __forceinline__ float tanhf_fast(float x){ return 1.f - 2.f/(1.f+__expf(2.f*x)); }

__device__ __forceinline__ uint64_t agload64(const uint64_t* p){
  return __hip_atomic_load(p, __ATOMIC_RELAXED, __HIP_MEMORY_SCOPE_AGENT);
}
__device__ __forceinline__ void agstore32(uint32_t* p, uint32_t v){
  __hip_atomic_store(p, v, __ATOMIC_RELAXED, __HIP_MEMORY_SCOPE_AGENT);
}
__device__ __forceinline__ uint32_t f2bf(float f){   // RNE f32->bf16 (finite inputs)
  uint32_t u = __float_as_uint(f);
  u += 0x7fffu + ((u>>16)&1u);
  return u>>16;
}
__device__ __forceinline__ bool pois(uint64_t v){
  return (((uint32_t)v)==POISON32) | (((uint32_t)(v>>32))==POISON32);
}
__device__ __forceinline__ void unpack_store(uint64_t v, float* buf, int gsw){
  uint32_t aa = (uint32_t)v, bb = (uint32_t)(v>>32);
  float4 f;
  f.x = __uint_as_float(aa<<16);
  f.y = __uint_as_float(aa & 0xffff0000u);
  f.z = __uint_as_float(bb<<16);
  f.w = __uint_as_float(bb & 0xffff0000u);
  *(float4*)&buf[gsw*4] = f;
}
__device__ __forceinline__ f4 ntload(const float* p){
  return __builtin_nontemporal_load((const f4*)p);
}

// pin weights in VGPRs: loop-carried "+v" dep => compiler cannot rematerialize/demote
#define PIN4(v) asm volatile("" : "+v"((v).x), "+v"((v).y), "+v"((v).z), "+v"((v).w))
#define PINS do { _Pragma("unroll") for (int _q=0;_q<16;_q++){ PIN4(wi[_q]); PIN4(wr[_q]); } } while(0)

// matvec over this thread's 64-wide K chunk from XOR-swizzled LDS vector
#define MV(bufptr, W) do { \
  const float* _b = (bufptr); \
  _Pragma("unroll") \
  for (int q=0;q<16;q++){ \
    float4 hv = *(const float4*)&_b[(((c<<4)|((q^c)&15))<<2)]; \
    s0 = fmaf(W[q].x, hv.x, s0); s1 = fmaf(W[q].y, hv.y, s1); \
    s2 = fmaf(W[q].z, hv.z, s2); s3 = fmaf(W[q].w, hv.w, s3); } \
} while(0)

// reduce 8 chunk-partials (adjacent lanes) -> row sum; gather 4 gates (rl strides of 8);
// lanes 0 and 32 of each wave own dims 2w, 2w+1
#define REDUCE_GATES_PUBLISH(dstp) do { \
  float s = (s0+s1)+(s2+s3); \
  s += __shfl_xor(s,1); s += __shfl_xor(s,2); s += __shfl_xor(s,4); \
  s += bias; \
  float fv = __shfl_down(s,8), gv = __shfl_down(s,16), ov = __shfl_down(s,24); \
  float gi = sigf(s), gf = sigf(fv), gg = tanhf_fast(gv), go = sigf(ov); \
  cst = fmaf(gf, cst, gi*gg); \
  float h = go * tanhf_fast(cst); \
  float ho = __shfl(h, 32); \
  if (lane == 0) agstore32((dstp) + (size_t)t*256 + wgl*8 + w, f2bf(h) | (f2bf(ho)<<16)); \
} while(0)

// ---- poison comm arrays (agent-scope stores) ----
__global__ __launch_bounds__(256,1)
void poison_kernel(uint64_t* __restrict__ a, int n64){
  const uint64_t P = 0x7FA57FA57FA57FA5ull;
  int i = blockIdx.x*256 + threadIdx.x;
  const int st = gridDim.x*256;
  for (; i < n64; i += st)
    __hip_atomic_store(a+i, P, __ATOMIC_RELAXED, __HIP_MEMORY_SCOPE_AGENT);
}

// ---- persistent 2-layer LSTM scan, data-flow synchronized, bf16 comm ----
__global__ __launch_bounds__(WGT, 2)
void lstm_persistent(const float* __restrict__ x,
                     const float* __restrict__ wih0, const float* __restrict__ whh0,
                     const float* __restrict__ bih0, const float* __restrict__ bhh0,
                     const float* __restrict__ wih1, const float* __restrict__ whh1,
                     const float* __restrict__ bih1, const float* __restrict__ bhh1,
                     uint32_t* __restrict__ hs0u, uint32_t* __restrict__ hs1u)
{
  const int wg    = blockIdx.x;
  const int layer = (wg >= NWGL) ? 1 : 0;
  const int wgl   = layer ? wg - NWGL : wg;
  const int tid   = threadIdx.x;
  const int w     = tid >> 6;
  const int lane  = tid & 63;
  const int rl    = lane >> 3;     // row-group within wave
  const int c     = lane & 7;      // K-chunk (64 wide)
  const int g     = rl & 3;        // gate (i,f,gc,o)
  const int dd    = rl >> 2;       // dim select within wave
  const int grow  = g*HDIM + wgl*DPW + 2*w + dd;   // global gate-row

  const float* Wih = layer ? wih1 : wih0;
  const float* Whh = layer ? whh1 : whh0;
  const float bias = (layer?bih1:bih0)[grow] + (layer?bhh1:bhh0)[grow];

  float4 wi[16], wr[16];
  {
    const float* wip = Wih + (size_t)grow*HDIM + c*64;
    const float* wrp = Whh + (size_t)grow*HDIM + c*64;
    #pragma unroll
    for (int q=0;q<16;q++){
      wi[q] = *(const float4*)(wip + 4*q);
      wr[q] = *(const float4*)(wrp + 4*q);
    }
  }

  __shared__ float xab[2][HDIM];   // step-input vector, double buffered, XOR-swizzled
  __shared__ float hrb[2][HDIM];   // recurrent vector, double buffered, XOR-swizzled

  const int t7  = tid & 127;
  const int gsw = t7 ^ ((t7>>4)&7);   // swizzled 16B-granule index (valid when tid<128)
  float cst = 0.f;

  if (!layer){
    // ---------------- layer 0: input = x (fp32, NT-prefetched) ----------------
    f4 xnext = (f4){0.f,0.f,0.f,0.f};
    if (tid < 128){
      f4 x0 = ntload(x + tid*4);
      *(f4*)&xab[0][gsw*4] = x0;
      xnext = ntload(x + HDIM + tid*4);
      *(f4*)&hrb[0][gsw*4] = (f4){0.f,0.f,0.f,0.f};
    }
    __syncthreads();

    #pragma unroll 1
    for (int t = 0; t < TSEQ; ++t){
      PINS;
      float s0=0.f,s1=0.f,s2=0.f,s3=0.f;
      const uint64_t* pp = (const uint64_t*)(hs0u + (size_t)(t-1)*256) + tid;
      uint64_t v = 0;
      const bool dp = (t > 0) && (tid < 128);
      if (dp) v = agload64(pp);              // issue early; check after Phase A
      // Phase A: ih matvec on x[t] (off the recurrent chain)
      MV(&xab[t&1][0], wi);
      if (tid < 128){
        *(f4*)&xab[(t+1)&1][gsw*4] = xnext;  // stage x[t+1]
        if (t+2 < TSEQ) xnext = ntload(x + (size_t)(t+2)*HDIM + tid*4);
        if (t > 0){
          while (pois(v)) v = agload64(pp);  // wait for h[t-1]
          unpack_store(v, &hrb[t&1][0], gsw);
        }
      }
      __syncthreads();
      // Phase C: hh matvec + reduce + gates + publish
      MV(&hrb[t&1][0], wr);
      REDUCE_GATES_PUBLISH(hs0u);
    }
  } else {
    // ---------------- layer 1: input = hs0 (bf16, polled) ----------------
    if (tid < 128) *(f4*)&hrb[0][gsw*4] = (f4){0.f,0.f,0.f,0.f};
    __syncthreads();

    #pragma unroll 1
    for (int t = 0; t < TSEQ; ++t){
      PINS;
      float s0=0.f,s1=0.f,s2=0.f,s3=0.f;
      if (tid < 128){
        const uint64_t* px = (const uint64_t*)(hs0u + (size_t)t*256) + tid;
        uint64_t v = agload64(px);
        while (pois(v)) v = agload64(px);    // hs0[t] (usually already arrived)
        unpack_store(v, &xab[t&1][0], gsw);
      }
      __syncthreads();
      const uint64_t* ph = (const uint64_t*)(hs1u + (size_t)(t-1)*256) + tid;
      uint64_t v2 = 0;
      const bool dp = (t > 0) && (tid < 128);
      if (dp) v2 = agload64(ph);             // issue early
      MV(&xab[t&1][0], wi);                  // ih matvec overlaps the wait
      if (dp){
        while (pois(v2)) v2 = agload64(ph);
        unpack_store(v2, &hrb[t&1][0], gsw);
      }
      __syncthreads();
      MV(&hrb[t&1][0], wr);
      REDUCE_GATES_PUBLISH(hs1u);
    }
  }
}

// ---- head ----
__global__ __launch_bounds__(256)
void transpose_kernel(const float* __restrict__ w1, const float* __restrict__ w2,
                      float* __restrict__ w1t, float* __restrict__ w2t){
  int i = blockIdx.x*256 + threadIdx.x;
  if (i < 128*512){ int rr = i >> 9, k = i & 511; w1t[k*128 + rr] = w1[i]; }
  if (i < 64*128){ int rr = i >> 7, k = i & 127; w2t[k*64 + rr] = w2[i]; }
}

__global__ __launch_bounds__(128)
void mlp1_kernel(const uint32_t* __restrict__ hs1u, const float* __restrict__ w1t,
                 const float* __restrict__ b1, float* __restrict__ z1){
  __shared__ float hsl[2048];             // 4 rows x 512
  const int tid = threadIdx.x;
  const size_t row0 = (size_t)blockIdx.x*4;
  const uint4* src = (const uint4*)(hs1u + row0*256);
  #pragma unroll
  for (int q=0;q<2;q++){
    int j = tid + q*128;                  // uint4 index 0..255
    uint4 u = src[j];
    int base = j*8;
    hsl[base+0] = __uint_as_float(u.x<<16); hsl[base+1] = __uint_as_float(u.x & 0xffff0000u);
    hsl[base+2] = __uint_as_float(u.y<<16); hsl[base+3] = __uint_as_float(u.y & 0xffff0000u);
    hsl[base+4] = __uint_as_float(u.z<<16); hsl[base+5] = __uint_as_float(u.z & 0xffff0000u);
    hsl[base+6] = __uint_as_float(u.w<<16); hsl[base+7] = __uint_as_float(u.w & 0xffff0000u);
  }
  __syncthreads();
  float a0=0.f,a1=0.f,a2=0.f,a3=0.f;
  #pragma unroll 4
  for (int k=0;k<512;k++){
    float wv = w1t[k*128 + tid];
    a0 = fmaf(wv, hsl[k],      a0);
    a1 = fmaf(wv, hsl[512+k],  a1);
    a2 = fmaf(wv, hsl[1024+k], a2);
    a3 = fmaf(wv, hsl[1536+k], a3);
  }
  float bb = b1[tid];
  z1[(row0+0)*128 + tid] = fmaxf(a0+bb, 0.f);
  z1[(row0+1)*128 + tid] = fmaxf(a1+bb, 0.f);
  z1[(row0+2)*128 + tid] = fmaxf(a2+bb, 0.f);
  z1[(row0+3)*128 + tid] = fmaxf(a3+bb, 0.f);
}

template<int NF_>
__global__ void stats_partial(const float* __restrict__ z, float* __restrict__ part){
  const int cf = threadIdx.x;
  const int b  = blockIdx.x;             // 64 blocks x 512 rows
  float s=0.f, sq=0.f;
  const float* p = z + (size_t)b*512*NF_ + cf;
  for (int rr=0; rr<512; rr++){
    float v = p[(size_t)rr*NF_];
    s += v; sq = fmaf(v, v, sq);
  }
  part[(b*NF_ + cf)*2+0] = s;
  part[(b*NF_ + cf)*2+1] = sq;
}

template<int NF_>
__global__ void stats_final(const float* __restrict__ part, const float* __restrict__ gamma,
                            const float* __restrict__ beta, float* __restrict__ sc,
                            float* __restrict__ sh){
  const int cf = threadIdx.x;
  float s=0.f, sq=0.f;
  for (int b=0;b<64;b++){ s += part[(b*NF_+cf)*2]; sq += part[(b*NF_+cf)*2+1]; }
  const float inv = 1.f/32768.f;
  float m = s*inv;
  float v = fmaf(sq, inv, -m*m);
  float scale = gamma[cf]*rsqrtf(v + 1e-5f);
  sc[cf] = scale;
  sh[cf] = fmaf(-m, scale, beta[cf]);
}

__global__ __launch_bounds__(64)
void mlp2_kernel(const float* __restrict__ z1, const float* __restrict__ w2t,
                 const float* __restrict__ b2, const float* __restrict__ sc1,
                 const float* __restrict__ sh1, float* __restrict__ z2){
  __shared__ float zl[1024];              // 8 rows x 128 (BN-applied)
  const int tid = threadIdx.x;
  const size_t row0 = (size_t)blockIdx.x*8;
  #pragma unroll
  for (int q=0;q<4;q++){
    int idx = tid + q*64;                 // float4 index 0..255
    float4 v = *(const float4*)&z1[row0*128 + idx*4];
    int k0 = (idx*4) & 127;
    v.x = fmaf(v.x, sc1[k0+0], sh1[k0+0]);
    v.y = fmaf(v.y, sc1[k0+1], sh1[k0+1]);
    v.z = fmaf(v.z, sc1[k0+2], sh1[k0+2]);
    v.w = fmaf(v.w, sc1[k0+3], sh1[k0+3]);
    *(float4*)&zl[idx*4] = v;
  }
  __syncthreads();
  float acc[8] = {0.f,0.f,0.f,0.f,0.f,0.f,0.f,0.f};
  #pragma unroll 4
  for (int k=0;k<128;k++){
    float wv = w2t[k*64 + tid];
    #pragma unroll
    for (int rr=0;rr<8;rr++) acc[rr] = fmaf(wv, zl[rr*128 + k], acc[rr]);
  }
  float bb = b2[tid];
  #pragma unroll
  for (int rr=0;rr<8;rr++)
    z2[(row0+rr)*64 + tid] = fmaxf(acc[rr]+bb, 0.f);
}

__global__ __launch_bounds__(256)
void mlp3_kernel(const float* __restrict__ z2, const float* __restrict__ w3,
                 const float* __restrict__ b3, const float* __restrict__ sc2,
                 const float* __restrict__ sh2, float* __restrict__ out){
  const int tid = threadIdx.x;
  const int lane = tid & 63;
  const size_t row = (size_t)blockIdx.x*4 + (tid>>6);   // one wave per row
  float v = fmaf(z2[row*64 + lane], sc2[lane], sh2[lane]);
  float p0 = v*w3[lane], p1 = v*w3[64+lane], p2 = v*w3[128+lane];
  #pragma unroll
  for (int off=32; off; off>>=1){
    p0 += __shfl_xor(p0, off);
    p1 += __shfl_xor(p1, off);
    p2 += __shfl_xor(p2, off);
  }
  if (lane == 0){
    out[row*3+0] = p0 + b3[0];
    out[row*3+1] = p1 + b3[1];
    out[row*3+2] = p2 + b3[2];
  }
}

extern "C" void kernel_launch(void* const* d_in, const int* in_sizes, int n_in,
                              void* d_out, int out_size, void* d_ws, size_t ws_size,
                              hipStream_t stream){
  (void)in_sizes; (void)n_in; (void)out_size;
  const float* x    = (const float*)d_in[0];
  const float* wih0 = (const float*)d_in[1];
  const float* whh0 = (const float*)d_in[2];
  const float* bih0 = (const float*)d_in[3];
  const float* bhh0 = (const float*)d_in[4];
  const float* wih1 = (const float*)d_in[5];
  const float* whh1 = (const float*)d_in[6];
  const float* bih1 = (const float*)d_in[7];
  const float* bhh1 = (const float*)d_in[8];
  const float* w1   = (const float*)d_in[9];
  const float* b1   = (const float*)d_in[10];
  const float* g1   = (const float*)d_in[11];
  const float* be1  = (const float*)d_in[12];
  const float* w2   = (const float*)d_in[13];
  const float* b2   = (const float*)d_in[14];
  const float* g2   = (const float*)d_in[15];
  const float* be2  = (const float*)d_in[16];
  const float* w3   = (const float*)d_in[17];
  const float* b3   = (const float*)d_in[18];
  float* out = (float*)d_out;

  // Fully disjoint workspace layout (round-2 bug: head scratch aliased hs0 while
  // transpose ran BEFORE the scan, clobbering comm rows ~24576+). Round 1 proved
  // ws_size >= 134 MB, so we can afford no aliasing at all.
  if (ws_size < (size_t)(96u<<20)) return;   // need ~89 MB, require 96 MB

  uint8_t* wb = (uint8_t*)d_ws;
  uint32_t* hs0u = (uint32_t*)wb;                        // [0,32MB): [32768][256] u32 (bf16x2)
  uint32_t* hs1u = (uint32_t*)(wb + (size_t)(32u<<20));  // [32,64MB)
  float* z1    = (float*)(wb + (size_t)(64u<<20));       // [64,80MB): [32768][128] f32
  float* z2    = (float*)(wb + (size_t)(80u<<20));       // [80,88MB): [32768][64]  f32
  float* w1t   = (float*)(wb + (size_t)(88u<<20));       // 256 KB
  float* w2t   = w1t + 65536;                            // 32 KB
  float* part1 = w2t + 8192;                             // [64][128][2]
  float* part2 = part1 + 16384;                          // [64][64][2]
  float* sc1   = part2 + 8192;
  float* sh1   = sc1 + 128;
  float* sc2   = sh1 + 128;
  float* sh2   = sc2 + 64;

  poison_kernel<<<1024, 256, 0, stream>>>((uint64_t*)wb, 8*1024*1024);
  transpose_kernel<<<256, 256, 0, stream>>>(w1, w2, w1t, w2t);
  lstm_persistent<<<2*NWGL, WGT, 0, stream>>>(x, wih0, whh0, bih0, bhh0,
                                              wih1, whh1, bih1, bhh1, hs0u, hs1u);
  mlp1_kernel<<<8192, 128, 0, stream>>>(hs1u, w1t, b1, z1);
  stats_partial<128><<<64, 128, 0, stream>>>(z1, part1);
  stats_final<128><<<1, 128, 0, stream>>>(part1, g1, be1, sc1, sh1);
  mlp2_kernel<<<4096, 64, 0, stream>>>(z1, w2t, b2, sc1, sh1, z2);
  stats_partial<64><<<64, 64, 0, stream>>>(z2, part2);
  stats_final<64><<<1, 64, 0, stream>>>(part2, g2, be2, sc2, sh2);
  mlp3_kernel<<<8192, 256, 0, stream>>>(z2, w3, b3, sc2, sh2, out);
}

// Round 4
// 111673.157 us; speedup vs baseline: 2.1356x; 2.1356x over previous
//
#include <hip/hip_runtime.h>
#include <stdint.h>

#define TSEQ 32768
#define HDIM 512
#define NWGL 128        // workgroups per layer (1 per CU, 256 total)
#define WGT  256        // threads per workgroup (4 waves)
#define POISON32 0x7FA57FA5u   // each u16 half is a bf16 NaN; finite h never produces it

typedef float f4 __attribute__((ext_vector_type(4)));

__device__ __forceinline__ float sigf(float x){ return 1.f/(1.f+__expf(-x)); }
__device__ __forceinline__ float tanhf_fast(float x){ return 1.f - 2.f/(1.f+__expf(2.f*x)); }

__device__ __forceinline__ uint64_t agload64(const uint64_t* p){
  return __hip_atomic_load(p, __ATOMIC_RELAXED, __HIP_MEMORY_SCOPE_AGENT);
}
__device__ __forceinline__ void agstore32(uint32_t* p, uint32_t v){
  __hip_atomic_store(p, v, __ATOMIC_RELAXED, __HIP_MEMORY_SCOPE_AGENT);
}
__device__ __forceinline__ uint32_t f2bf(float f){   // RNE f32->bf16 (finite inputs)
  uint32_t u = __float_as_uint(f);
  u += 0x7fffu + ((u>>16)&1u);
  return u>>16;
}
__device__ __forceinline__ bool pois(uint64_t v){
  return (((uint32_t)v)==POISON32) | (((uint32_t)(v>>32))==POISON32);
}
__device__ __forceinline__ void unpack_store(uint64_t v, float* buf, int swg){
  uint32_t aa = (uint32_t)v, bb = (uint32_t)(v>>32);
  float4 f;
  f.x = __uint_as_float(aa<<16);
  f.y = __uint_as_float(aa & 0xffff0000u);
  f.z = __uint_as_float(bb<<16);
  f.w = __uint_as_float(bb & 0xffff0000u);
  *(float4*)&buf[swg*4] = f;
}
__device__ __forceinline__ f4 ntload(const float* p){
  return __builtin_nontemporal_load((const f4*)p);
}

#define PIN4(v) asm volatile("" : "+v"((v).x), "+v"((v).y), "+v"((v).z), "+v"((v).w))

// matvec over this thread's 32-wide K chunk from XOR-swizzled LDS vector
// granule layout: logical granule g stored at (g&~7) | ((g&7) ^ ((g>>3)&7))
#define MV(bufptr, W) do { \
  const float* _b = (bufptr); \
  _Pragma("unroll") \
  for (int q=0;q<8;q++){ \
    float4 hv = *(const float4*)&_b[(((c<<3) | (q ^ (c&7)))<<2)]; \
    s0 = fmaf(W[q].x, hv.x, s0); s1 = fmaf(W[q].y, hv.y, s1); \
    s2 = fmaf(W[q].z, hv.z, s2); s3 = fmaf(W[q].w, hv.w, s3); } \
} while(0)

// ---- poison comm arrays (agent-scope stores) ----
__global__ __launch_bounds__(256,1)
void poison_kernel(uint64_t* __restrict__ a, int n64){
  const uint64_t P = 0x7FA57FA57FA57FA5ull;
  int i = blockIdx.x*256 + threadIdx.x;
  const int st = gridDim.x*256;
  for (; i < n64; i += st)
    __hip_atomic_store(a+i, P, __ATOMIC_RELAXED, __HIP_MEMORY_SCOPE_AGENT);
}

// ---- persistent 2-layer LSTM scan, data-flow synchronized, bf16 comm ----
// 256 wgs x 256 thr: wg<128 -> layer0, wg>=128 -> layer1. Per wg: 16 gate rows
// (4 dims x 4 gates). Thread (c = tid>>4, r = tid&15): row r, K-chunk [c*32,c*32+32).
__global__ __launch_bounds__(WGT, 1)
void lstm_persistent(const float* __restrict__ x,
                     const float* __restrict__ wih0, const float* __restrict__ whh0,
                     const float* __restrict__ bih0, const float* __restrict__ bhh0,
                     const float* __restrict__ wih1, const float* __restrict__ whh1,
                     const float* __restrict__ bih1, const float* __restrict__ bhh1,
                     uint32_t* __restrict__ hs0u, uint32_t* __restrict__ hs1u)
{
  const int wg    = blockIdx.x;
  const int layer = (wg >= NWGL) ? 1 : 0;
  const int wgl   = layer ? wg - NWGL : wg;
  const int tid   = threadIdx.x;
  const int c     = tid >> 4;
  const int r     = tid & 15;
  const int grow  = (r>>2)*HDIM + wgl*4 + (r&3);   // gate (r>>2), dim wgl*4+(r&3)

  const float* Wih = layer ? wih1 : wih0;
  const float* Whh = layer ? whh1 : whh0;
  uint32_t* dst = layer ? hs1u : hs0u;

  float bias = 0.f;
  if (tid < 16){
    int br = (tid>>2)*HDIM + wgl*4 + (tid&3);
    bias = (layer?bih1:bih0)[br] + (layer?bhh1:bhh0)[br];
  }

  // 64 weight floats/thread -> stays in VGPRs without pressure (round-1's 128 demoted)
  float4 wi[8], wr[8];
  {
    const float* wip = Wih + (size_t)grow*HDIM + c*32;
    const float* wrp = Whh + (size_t)grow*HDIM + c*32;
    #pragma unroll
    for (int q=0;q<8;q++){
      wi[q] = *(const float4*)(wip + 4*q);
      wr[q] = *(const float4*)(wrp + 4*q);
    }
  }
  // one-time pin (outside the loop; prevents load-sinking, no per-iter cost)
  #pragma unroll
  for (int q=0;q<8;q++){ PIN4(wi[q]); PIN4(wr[q]); }

  __shared__ float xab[2][HDIM];   // step-input vector, double buffered, swizzled
  __shared__ float hrb[2][HDIM];   // recurrent vector, double buffered, swizzled
  __shared__ float part[64];       // 4 waves x 16 row-partials

  const int j   = tid - 128;                 // stager index (tid>=128)
  const int sg  = tid & 127;
  const int swg = (sg & ~7) | ((sg&7) ^ ((sg>>3)&7));   // swizzled granule
  float cst = 0.f;                           // cell state (lanes 0-3 meaningful)
  f4 xpref = (f4){0.f,0.f,0.f,0.f};

  // ---- pre-loop: stage xab[0], hrb[0]=0 ----
  if (tid < 128){
    *(f4*)&hrb[0][swg*4] = (f4){0.f,0.f,0.f,0.f};
  } else if (!layer){
    *(f4*)&xab[0][swg*4] = ntload(x + j*4);        // x[0]
    xpref = ntload(x + HDIM + j*4);                // x[1]
  } else {
    const uint64_t* p = (const uint64_t*)hs0u + j; // hs0[0]
    uint64_t v = agload64(p);
    while (pois(v)) v = agload64(p);
    unpack_store(v, &xab[0][0], swg);
  }
  __syncthreads();

  #pragma unroll 1
  for (int t = 0; t < TSEQ; ++t){
    float s0=0.f, s1=0.f, s2=0.f, s3=0.f;

    // issue poll loads early (latency overlaps MV(wi))
    const uint64_t* pp = nullptr;
    uint64_t v = 0;
    if (tid < 128){
      if (t > 0){ pp = (const uint64_t*)(dst + (size_t)(t-1)*256) + tid; v = agload64(pp); }
    } else if (layer){
      if (t+1 < TSEQ){ pp = (const uint64_t*)(hs0u + (size_t)(t+1)*256) + j; v = agload64(pp); }
    }

    // ih matvec on input staged one iteration ago (off the recurrent chain)
    MV(&xab[t&1][0], wi);

    if (tid < 128){
      if (t > 0){
        while (pois(v)) v = agload64(pp);          // wait for h[t-1]
        unpack_store(v, &hrb[t&1][0], swg);
      }
    } else if (!layer){
      if (t+1 < TSEQ){
        *(f4*)&xab[(t+1)&1][swg*4] = xpref;        // stage x[t+1]
        if (t+2 < TSEQ) xpref = ntload(x + (size_t)(t+2)*HDIM + j*4);
      }
    } else {
      if (t+1 < TSEQ){
        while (pois(v)) v = agload64(pp);          // hs0[t+1]: layer0 runs ahead -> cheap
        unpack_store(v, &xab[(t+1)&1][0], swg);
      }
    }
    __syncthreads();

    // hh matvec + reduce + gates + publish
    MV(&hrb[t&1][0], wr);
    float s = (s0+s1)+(s2+s3);
    s += __shfl_xor(s,16); s += __shfl_xor(s,32);  // sum this wave's 4 K-chunks
    if ((tid & 63) < 16) part[(tid>>6)*16 + (tid&15)] = s;
    __syncthreads();
    if (tid < 16){
      float rs = part[tid] + part[16+tid] + part[32+tid] + part[48+tid] + bias;
      float fv = __shfl_down(rs,4), gv = __shfl_down(rs,8), ov = __shfl_down(rs,12);
      float gi = sigf(rs), gf = sigf(fv), gg = tanhf_fast(gv), go = sigf(ov);
      cst = fmaf(gf, cst, gi*gg);
      float h = go * tanhf_fast(cst);
      float ho = __shfl_down(h,1);
      if ((tid&1)==0 && tid<4)
        agstore32(dst + (size_t)t*256 + wgl*2 + (tid>>1), f2bf(h) | (f2bf(ho)<<16));
    }
  }
}

// ---- head ----
__global__ __launch_bounds__(256)
void transpose_kernel(const float* __restrict__ w1, const float* __restrict__ w2,
                      float* __restrict__ w1t, float* __restrict__ w2t){
  int i = blockIdx.x*256 + threadIdx.x;
  if (i < 128*512){ int rr = i >> 9, k = i & 511; w1t[k*128 + rr] = w1[i]; }
  if (i < 64*128){ int rr = i >> 7, k = i & 127; w2t[k*64 + rr] = w2[i]; }
}

__global__ __launch_bounds__(128)
void mlp1_kernel(const uint32_t* __restrict__ hs1u, const float* __restrict__ w1t,
                 const float* __restrict__ b1, float* __restrict__ z1){
  __shared__ float hsl[2048];             // 4 rows x 512
  const int tid = threadIdx.x;
  const size_t row0 = (size_t)blockIdx.x*4;
  const uint4* src = (const uint4*)(hs1u + row0*256);
  #pragma unroll
  for (int q=0;q<2;q++){
    int jj = tid + q*128;                 // uint4 index 0..255
    uint4 u = src[jj];
    int base = jj*8;
    hsl[base+0] = __uint_as_float(u.x<<16); hsl[base+1] = __uint_as_float(u.x & 0xffff0000u);
    hsl[base+2] = __uint_as_float(u.y<<16); hsl[base+3] = __uint_as_float(u.y & 0xffff0000u);
    hsl[base+4] = __uint_as_float(u.z<<16); hsl[base+5] = __uint_as_float(u.z & 0xffff0000u);
    hsl[base+6] = __uint_as_float(u.w<<16); hsl[base+7] = __uint_as_float(u.w & 0xffff0000u);
  }
  __syncthreads();
  float a0=0.f,a1=0.f,a2=0.f,a3=0.f;
  #pragma unroll 4
  for (int k=0;k<512;k++){
    float wv = w1t[k*128 + tid];
    a0 = fmaf(wv, hsl[k],      a0);
    a1 = fmaf(wv, hsl[512+k],  a1);
    a2 = fmaf(wv, hsl[1024+k], a2);
    a3 = fmaf(wv, hsl[1536+k], a3);
  }
  float bb = b1[tid];
  z1[(row0+0)*128 + tid] = fmaxf(a0+bb, 0.f);
  z1[(row0+1)*128 + tid] = fmaxf(a1+bb, 0.f);
  z1[(row0+2)*128 + tid] = fmaxf(a2+bb, 0.f);
  z1[(row0+3)*128 + tid] = fmaxf(a3+bb, 0.f);
}

template<int NF_>
__global__ void stats_partial(const float* __restrict__ z, float* __restrict__ part){
  const int cf = threadIdx.x;
  const int b  = blockIdx.x;             // 64 blocks x 512 rows
  float s=0.f, sq=0.f;
  const float* p = z + (size_t)b*512*NF_ + cf;
  for (int rr=0; rr<512; rr++){
    float v = p[(size_t)rr*NF_];
    s += v; sq = fmaf(v, v, sq);
  }
  part[(b*NF_ + cf)*2+0] = s;
  part[(b*NF_ + cf)*2+1] = sq;
}

template<int NF_>
__global__ void stats_final(const float* __restrict__ part, const float* __restrict__ gamma,
                            const float* __restrict__ beta, float* __restrict__ sc,
                            float* __restrict__ sh){
  const int cf = threadIdx.x;
  float s=0.f, sq=0.f;
  for (int b=0;b<64;b++){ s += part[(b*NF_+cf)*2]; sq += part[(b*NF_+cf)*2+1]; }
  const float inv = 1.f/32768.f;
  float m = s*inv;
  float v = fmaf(sq, inv, -m*m);
  float scale = gamma[cf]*rsqrtf(v + 1e-5f);
  sc[cf] = scale;
  sh[cf] = fmaf(-m, scale, beta[cf]);
}

__global__ __launch_bounds__(64)
void mlp2_kernel(const float* __restrict__ z1, const float* __restrict__ w2t,
                 const float* __restrict__ b2, const float* __restrict__ sc1,
                 const float* __restrict__ sh1, float* __restrict__ z2){
  __shared__ float zl[1024];              // 8 rows x 128 (BN-applied)
  const int tid = threadIdx.x;
  const size_t row0 = (size_t)blockIdx.x*8;
  #pragma unroll
  for (int q=0;q<4;q++){
    int idx = tid + q*64;                 // float4 index 0..255
    float4 v = *(const float4*)&z1[row0*128 + idx*4];
    int k0 = (idx*4) & 127;
    v.x = fmaf(v.x, sc1[k0+0], sh1[k0+0]);
    v.y = fmaf(v.y, sc1[k0+1], sh1[k0+1]);
    v.z = fmaf(v.z, sc1[k0+2], sh1[k0+2]);
    v.w = fmaf(v.w, sc1[k0+3], sh1[k0+3]);
    *(float4*)&zl[idx*4] = v;
  }
  __syncthreads();
  float acc[8] = {0.f,0.f,0.f,0.f,0.f,0.f,0.f,0.f};
  #pragma unroll 4
  for (int k=0;k<128;k++){
    float wv = w2t[k*64 + tid];
    #pragma unroll
    for (int rr=0;rr<8;rr++) acc[rr] = fmaf(wv, zl[rr*128 + k], acc[rr]);
  }
  float bb = b2[tid];
  #pragma unroll
  for (int rr=0;rr<8;rr++)
    z2[(row0+rr)*64 + tid] = fmaxf(acc[rr]+bb, 0.f);
}

__global__ __launch_bounds__(256)
void mlp3_kernel(const float* __restrict__ z2, const float* __restrict__ w3,
                 const float* __restrict__ b3, const float* __restrict__ sc2,
                 const float* __restrict__ sh2, float* __restrict__ out){
  const int tid = threadIdx.x;
  const int lane = tid & 63;
  const size_t row = (size_t)blockIdx.x*4 + (tid>>6);   // one wave per row
  float v = fmaf(z2[row*64 + lane], sc2[lane], sh2[lane]);
  float p0 = v*w3[lane], p1 = v*w3[64+lane], p2 = v*w3[128+lane];
  #pragma unroll
  for (int off=32; off; off>>=1){
    p0 += __shfl_xor(p0, off);
    p1 += __shfl_xor(p1, off);
    p2 += __shfl_xor(p2, off);
  }
  if (lane == 0){
    out[row*3+0] = p0 + b3[0];
    out[row*3+1] = p1 + b3[1];
    out[row*3+2] = p2 + b3[2];
  }
}

extern "C" void kernel_launch(void* const* d_in, const int* in_sizes, int n_in,
                              void* d_out, int out_size, void* d_ws, size_t ws_size,
                              hipStream_t stream){
  (void)in_sizes; (void)n_in; (void)out_size;
  const float* x    = (const float*)d_in[0];
  const float* wih0 = (const float*)d_in[1];
  const float* whh0 = (const float*)d_in[2];
  const float* bih0 = (const float*)d_in[3];
  const float* bhh0 = (const float*)d_in[4];
  const float* wih1 = (const float*)d_in[5];
  const float* whh1 = (const float*)d_in[6];
  const float* bih1 = (const float*)d_in[7];
  const float* bhh1 = (const float*)d_in[8];
  const float* w1   = (const float*)d_in[9];
  const float* b1   = (const float*)d_in[10];
  const float* g1   = (const float*)d_in[11];
  const float* be1  = (const float*)d_in[12];
  const float* w2   = (const float*)d_in[13];
  const float* b2   = (const float*)d_in[14];
  const float* g2   = (const float*)d_in[15];
  const float* be2  = (const float*)d_in[16];
  const float* w3   = (const float*)d_in[17];
  const float* b3   = (const float*)d_in[18];
  float* out = (float*)d_out;

  // Fully disjoint workspace layout (round-2 lesson: no aliasing, ever).
  if (ws_size < (size_t)(96u<<20)) return;

  uint8_t* wb = (uint8_t*)d_ws;
  uint32_t* hs0u = (uint32_t*)wb;                        // [0,32MB): [32768][256] u32 (bf16x2)
  uint32_t* hs1u = (uint32_t*)(wb + (size_t)(32u<<20));  // [32,64MB)
  float* z1    = (float*)(wb + (size_t)(64u<<20));       // [64,80MB): [32768][128] f32
  float* z2    = (float*)(wb + (size_t)(80u<<20));       // [80,88MB): [32768][64]  f32
  float* w1t   = (float*)(wb + (size_t)(88u<<20));       // 256 KB
  float* w2t   = w1t + 65536;                            // 32 KB
  float* part1 = w2t + 8192;                             // [64][128][2]
  float* part2 = part1 + 16384;                          // [64][64][2]
  float* sc1   = part2 + 8192;
  float* sh1   = sc1 + 128;
  float* sc2   = sh1 + 128;
  float* sh2   = sc2 + 64;

  poison_kernel<<<1024, 256, 0, stream>>>((uint64_t*)wb, 8*1024*1024);
  transpose_kernel<<<256, 256, 0, stream>>>(w1, w2, w1t, w2t);
  lstm_persistent<<<2*NWGL, WGT, 0, stream>>>(x, wih0, whh0, bih0, bhh0,
                                              wih1, whh1, bih1, bhh1, hs0u, hs1u);
  mlp1_kernel<<<8192, 128, 0, stream>>>(hs1u, w1t, b1, z1);
  stats_partial<128><<<64, 128, 0, stream>>>(z1, part1);
  stats_final<128><<<1, 128, 0, stream>>>(part1, g1, be1, sc1, sh1);
  mlp2_kernel<<<4096, 64, 0, stream>>>(z1, w2t, b2, sc1, sh1, z2);
  stats_partial<64><<<64, 64, 0, stream>>>(z2, part2);
  stats_final<64><<<1, 64, 0, stream>>>(part2, g2, be2, sc2, sh2);
  mlp3_kernel<<<8192, 256, 0, stream>>>(z2, w3, b3, sc2, sh2, out);
}

// Round 5
// 109467.236 us; speedup vs baseline: 2.1787x; 1.0202x over previous
//
#include <hip/hip_runtime.h>
#include <stdint.h>

#define TSEQ 32768
#define HDIM 512
#define NWGL 32         // workgroups per layer (64 total, 1 per CU)
#define WGT  512        // threads per workgroup (8 waves)
#define POISON32 0x7FA57FA5u   // NaN pattern; finite values never equal it

typedef float f4 __attribute__((ext_vector_type(4)));

__device__ __forceinline__ float sigf(float x){ return 1.f/(1.f+__expf(-x)); }
__device__ __forceinline__ float tanhf_fast(float x){ return 1.f - 2.f/(1.f+__expf(2.f*x)); }

__device__ __forceinline__ uint64_t agload64(const uint64_t* p){
  return __hip_atomic_load(p, __ATOMIC_RELAXED, __HIP_MEMORY_SCOPE_AGENT);
}
__device__ __forceinline__ void agstore32(uint32_t* p, uint32_t v){
  __hip_atomic_store(p, v, __ATOMIC_RELAXED, __HIP_MEMORY_SCOPE_AGENT);
}
__device__ __forceinline__ bool pois2(uint64_t v){
  return (((uint32_t)v)==POISON32) | (((uint32_t)(v>>32))==POISON32);
}
__device__ __forceinline__ f4 asf4(uint64_t a, uint64_t b){
  f4 f; f.x=__uint_as_float((uint32_t)a); f.y=__uint_as_float((uint32_t)(a>>32));
        f.z=__uint_as_float((uint32_t)b); f.w=__uint_as_float((uint32_t)(b>>32));
  return f;
}
__device__ __forceinline__ f4 ntload(const float* p){
  return __builtin_nontemporal_load((const f4*)p);
}
// 16B-granule XOR swizzle: granule g -> (g & ~15) | ((g&15) ^ (g>>4))
__device__ __forceinline__ int swz(int g){ return (g & ~15) | ((g & 15) ^ (g >> 4)); }

#define PIN4(v) asm volatile("" : "+v"((v).x), "+v"((v).y), "+v"((v).z), "+v"((v).w))

// matvec over this thread's 64-wide K chunk (kc) from swizzled LDS vector.
// For fixed q, the 8 kc-groups hit 8 distinct bank-quads -> conflict-free b128.
#define MV(bufptr, W) do { \
  const float* _b = (bufptr); \
  _Pragma("unroll") \
  for (int q=0;q<16;q++){ \
    f4 hv = *(const f4*)&_b[(((kc<<4)|(q^kc))<<2)]; \
    s0 = fmaf(W[q].x, hv.x, s0); s1 = fmaf(W[q].y, hv.y, s1); \
    s2 = fmaf(W[q].z, hv.z, s2); s3 = fmaf(W[q].w, hv.w, s3); } \
} while(0)

// ---- poison comm arrays (agent-scope stores) ----
__global__ __launch_bounds__(256,1)
void poison_kernel(uint64_t* __restrict__ a, int n64){
  const uint64_t P = (((uint64_t)POISON32)<<32) | (uint64_t)POISON32;
  int i = blockIdx.x*256 + threadIdx.x;
  const int st = gridDim.x*256;
  for (; i < n64; i += st)
    __hip_atomic_store(a+i, P, __ATOMIC_RELAXED, __HIP_MEMORY_SCOPE_AGENT);
}

// ---- persistent 2-layer LSTM scan ----
// 64 wgs x 512 thr. wg<32 -> layer0 (input x), wg>=32 -> layer1 (input hs0).
// Per wg: 64 gate rows = 16 dims x 4 gates; row = 4*dl + g; thread = row*8 + kc.
// Publish: 16 f32 (one 64B line per wg per step), fp32 comm, data-as-flag.
__global__ __launch_bounds__(WGT, 2)
void lstm_persistent(const float* __restrict__ x,
                     const float* __restrict__ wih0, const float* __restrict__ whh0,
                     const float* __restrict__ bih0, const float* __restrict__ bhh0,
                     const float* __restrict__ wih1, const float* __restrict__ whh1,
                     const float* __restrict__ bih1, const float* __restrict__ bhh1,
                     float* __restrict__ hs0, float* __restrict__ hs1)
{
  const int wg    = blockIdx.x;
  const int layer = (wg >= NWGL) ? 1 : 0;
  const int wgl   = layer ? wg - NWGL : wg;
  const int tid   = threadIdx.x;
  const int kc    = tid & 7;        // K-chunk [kc*64, kc*64+64)
  const int row   = tid >> 3;       // 0..63 local gate row
  const int dl    = row >> 2;       // 0..15 local dim
  const int g     = row & 3;        // gate: 0=i 1=f 2=g 3=o
  const int grow  = g*HDIM + wgl*16 + dl;
  const int lane  = tid & 63;
  const int wv    = tid >> 6;

  const float* Wih = layer ? wih1 : wih0;
  const float* Whh = layer ? whh1 : whh0;
  float* dst = layer ? hs1 : hs0;
  const float bias = (layer?bih1:bih0)[grow] + (layer?bhh1:bhh0)[grow];

  // 128 weight floats/thread; launch_bounds(512,2) -> 256 VGPR cap, no demotion pressure
  f4 wi[16], wr[16];
  {
    const float* wip = Wih + (size_t)grow*HDIM + kc*64;
    const float* wrp = Whh + (size_t)grow*HDIM + kc*64;
    #pragma unroll
    for (int q=0;q<16;q++){ wi[q] = *(const f4*)(wip+4*q); wr[q] = *(const f4*)(wrp+4*q); }
  }
  #pragma unroll
  for (int q=0;q<16;q++){ PIN4(wi[q]); PIN4(wr[q]); }   // one-time pin

  __shared__ float xa[2][HDIM];   // step input, double buffered, swizzled
  __shared__ float hr[2][HDIM];   // recurrent h, double buffered, swizzled

  float cst = 0.f;                // cell state (publisher lanes)
  f4 xpref = (f4){0.f,0.f,0.f,0.f};

  // ---- pre-loop staging ----
  if (tid < 128){
    *(f4*)&hr[0][swz(tid)*4] = (f4){0.f,0.f,0.f,0.f};
  } else if (tid < 256){
    const int j = tid - 128;
    if (!layer){
      *(f4*)&xa[0][swz(j)*4] = ntload(x + j*4);
      xpref = ntload(x + HDIM + j*4);
    } else {
      const uint64_t* p = (const uint64_t*)hs0 + j*2;
      uint64_t a = agload64(p), b = agload64(p+1);
      while (pois2(a)) a = agload64(p);
      while (pois2(b)) b = agload64(p+1);
      *(f4*)&xa[0][swz(j)*4] = asf4(a,b);
    }
  }
  __syncthreads();

  #pragma unroll 1
  for (int t = 0; t < TSEQ; ++t){
    // (a) issue polls early: latency overlaps the ih matvec
    const uint64_t *ph = nullptr, *px = nullptr;
    uint64_t h0=0, h1=0, x0=0, x1=0;
    if (tid < 128){
      if (t > 0){
        ph = (const uint64_t*)(dst + (size_t)(t-1)*HDIM) + tid*2;
        h0 = agload64(ph); h1 = agload64(ph+1);
      }
    } else if (tid < 256 && layer){
      if (t+1 < TSEQ){
        px = (const uint64_t*)(hs0 + (size_t)(t+1)*HDIM) + (tid-128)*2;
        x0 = agload64(px); x1 = agload64(px+1);
      }
    }

    // (b) ih matvec on input staged last iteration (off recurrent chain)
    float s0=0.f, s1=0.f, s2=0.f, s3=0.f;
    MV(&xa[t&1][0], wi);

    // (c) staging for this step's hr and next step's input
    if (tid < 128){
      if (t > 0){
        while (pois2(h0)) h0 = agload64(ph);
        while (pois2(h1)) h1 = agload64(ph+1);
        *(f4*)&hr[t&1][swz(tid)*4] = asf4(h0,h1);
      }
    } else if (tid < 256){
      const int j = tid - 128;
      if (!layer){
        if (t+1 < TSEQ){
          *(f4*)&xa[(t+1)&1][swz(j)*4] = xpref;
          const int tn = (t+2 < TSEQ) ? t+2 : t;
          xpref = ntload(x + (size_t)tn*HDIM + j*4);
        }
      } else {
        if (t+1 < TSEQ){
          while (pois2(x0)) x0 = agload64(px);
          while (pois2(x1)) x1 = agload64(px+1);
          *(f4*)&xa[(t+1)&1][swz(j)*4] = asf4(x0,x1);
        }
      }
    }
    __syncthreads();   // single barrier per step

    // (e) hh matvec + in-wave reduce + gates + publish
    MV(&hr[t&1][0], wr);
    float s = (s0+s1)+(s2+s3);
    s += __shfl_xor(s,1); s += __shfl_xor(s,2); s += __shfl_xor(s,4);
    s += bias;
    float fv = __shfl_down(s,8), gv = __shfl_down(s,16), ov = __shfl_down(s,24);
    if ((lane & 31) == 0){
      float gi = sigf(s), gf = sigf(fv), gg = tanhf_fast(gv), go = sigf(ov);
      cst = fmaf(gf, cst, gi*gg);
      float h = go * tanhf_fast(cst);
      agstore32((uint32_t*)(dst + (size_t)t*HDIM + wgl*16 + 2*wv + (lane>>5)),
                __float_as_uint(h));
    }
  }
}

// ---- head ----
__global__ __launch_bounds__(256)
void transpose_kernel(const float* __restrict__ w1, const float* __restrict__ w2,
                      float* __restrict__ w1t, float* __restrict__ w2t){
  int i = blockIdx.x*256 + threadIdx.x;
  if (i < 128*512){ int rr = i >> 9, k = i & 511; w1t[k*128 + rr] = w1[i]; }
  if (i < 64*128){ int rr = i >> 7, k = i & 127; w2t[k*64 + rr] = w2[i]; }
}

__global__ __launch_bounds__(128)
void mlp1_kernel(const float* __restrict__ hs1, const float* __restrict__ w1t,
                 const float* __restrict__ b1, float* __restrict__ z1){
  __shared__ float hsl[2048];             // 4 rows x 512
  const int tid = threadIdx.x;
  const size_t row0 = (size_t)blockIdx.x*4;
  #pragma unroll
  for (int q=0;q<4;q++){
    int idx = tid + q*128;
    *(float4*)&hsl[idx*4] = *(const float4*)&hs1[row0*512 + idx*4];
  }
  __syncthreads();
  float a0=0.f,a1=0.f,a2=0.f,a3=0.f;
  #pragma unroll 4
  for (int k=0;k<512;k++){
    float wv = w1t[k*128 + tid];
    a0 = fmaf(wv, hsl[k],      a0);
    a1 = fmaf(wv, hsl[512+k],  a1);
    a2 = fmaf(wv, hsl[1024+k], a2);
    a3 = fmaf(wv, hsl[1536+k], a3);
  }
  float bb = b1[tid];
  z1[(row0+0)*128 + tid] = fmaxf(a0+bb, 0.f);
  z1[(row0+1)*128 + tid] = fmaxf(a1+bb, 0.f);
  z1[(row0+2)*128 + tid] = fmaxf(a2+bb, 0.f);
  z1[(row0+3)*128 + tid] = fmaxf(a3+bb, 0.f);
}

template<int NF_>
__global__ void stats_partial(const float* __restrict__ z, float* __restrict__ part){
  const int cf = threadIdx.x;
  const int b  = blockIdx.x;             // 64 blocks x 512 rows
  float s=0.f, sq=0.f;
  const float* p = z + (size_t)b*512*NF_ + cf;
  for (int rr=0; rr<512; rr++){
    float v = p[(size_t)rr*NF_];
    s += v; sq = fmaf(v, v, sq);
  }
  part[(b*NF_ + cf)*2+0] = s;
  part[(b*NF_ + cf)*2+1] = sq;
}

template<int NF_>
__global__ void stats_final(const float* __restrict__ part, const float* __restrict__ gamma,
                            const float* __restrict__ beta, float* __restrict__ sc,
                            float* __restrict__ sh){
  const int cf = threadIdx.x;
  float s=0.f, sq=0.f;
  for (int b=0;b<64;b++){ s += part[(b*NF_+cf)*2]; sq += part[(b*NF_+cf)*2+1]; }
  const float inv = 1.f/32768.f;
  float m = s*inv;
  float v = fmaf(sq, inv, -m*m);
  float scale = gamma[cf]*rsqrtf(v + 1e-5f);
  sc[cf] = scale;
  sh[cf] = fmaf(-m, scale, beta[cf]);
}

__global__ __launch_bounds__(64)
void mlp2_kernel(const float* __restrict__ z1, const float* __restrict__ w2t,
                 const float* __restrict__ b2, const float* __restrict__ sc1,
                 const float* __restrict__ sh1, float* __restrict__ z2){
  __shared__ float zl[1024];              // 8 rows x 128 (BN-applied)
  const int tid = threadIdx.x;
  const size_t row0 = (size_t)blockIdx.x*8;
  #pragma unroll
  for (int q=0;q<4;q++){
    int idx = tid + q*64;                 // float4 index 0..255
    float4 v = *(const float4*)&z1[row0*128 + idx*4];
    int k0 = (idx*4) & 127;
    v.x = fmaf(v.x, sc1[k0+0], sh1[k0+0]);
    v.y = fmaf(v.y, sc1[k0+1], sh1[k0+1]);
    v.z = fmaf(v.z, sc1[k0+2], sh1[k0+2]);
    v.w = fmaf(v.w, sc1[k0+3], sh1[k0+3]);
    *(float4*)&zl[idx*4] = v;
  }
  __syncthreads();
  float acc[8] = {0.f,0.f,0.f,0.f,0.f,0.f,0.f,0.f};
  #pragma unroll 4
  for (int k=0;k<128;k++){
    float wv = w2t[k*64 + tid];
    #pragma unroll
    for (int rr=0;rr<8;rr++) acc[rr] = fmaf(wv, zl[rr*128 + k], acc[rr]);
  }
  float bb = b2[tid];
  #pragma unroll
  for (int rr=0;rr<8;rr++)
    z2[(row0+rr)*64 + tid] = fmaxf(acc[rr]+bb, 0.f);
}

__global__ __launch_bounds__(256)
void mlp3_kernel(const float* __restrict__ z2, const float* __restrict__ w3,
                 const float* __restrict__ b3, const float* __restrict__ sc2,
                 const float* __restrict__ sh2, float* __restrict__ out){
  const int tid = threadIdx.x;
  const int lane = tid & 63;
  const size_t row = (size_t)blockIdx.x*4 + (tid>>6);   // one wave per row
  float v = fmaf(z2[row*64 + lane], sc2[lane], sh2[lane]);
  float p0 = v*w3[lane], p1 = v*w3[64+lane], p2 = v*w3[128+lane];
  #pragma unroll
  for (int off=32; off; off>>=1){
    p0 += __shfl_xor(p0, off);
    p1 += __shfl_xor(p1, off);
    p2 += __shfl_xor(p2, off);
  }
  if (lane == 0){
    out[row*3+0] = p0 + b3[0];
    out[row*3+1] = p1 + b3[1];
    out[row*3+2] = p2 + b3[2];
  }
}

extern "C" void kernel_launch(void* const* d_in, const int* in_sizes, int n_in,
                              void* d_out, int out_size, void* d_ws, size_t ws_size,
                              hipStream_t stream){
  (void)in_sizes; (void)n_in; (void)out_size;
  const float* x    = (const float*)d_in[0];
  const float* wih0 = (const float*)d_in[1];
  const float* whh0 = (const float*)d_in[2];
  const float* bih0 = (const float*)d_in[3];
  const float* bhh0 = (const float*)d_in[4];
  const float* wih1 = (const float*)d_in[5];
  const float* whh1 = (const float*)d_in[6];
  const float* bih1 = (const float*)d_in[7];
  const float* bhh1 = (const float*)d_in[8];
  const float* w1   = (const float*)d_in[9];
  const float* b1   = (const float*)d_in[10];
  const float* g1   = (const float*)d_in[11];
  const float* be1  = (const float*)d_in[12];
  const float* w2   = (const float*)d_in[13];
  const float* b2   = (const float*)d_in[14];
  const float* g2   = (const float*)d_in[15];
  const float* be2  = (const float*)d_in[16];
  const float* w3   = (const float*)d_in[17];
  const float* b3   = (const float*)d_in[18];
  float* ws  = (float*)d_ws;
  float* out = (float*)d_out;

  if (ws_size < (size_t)134217728ull) return;   // proven available in round 1

  // comm buffers (disjoint, fp32): [0,64MB) hs0, [64,128MB) hs1
  float* hs0 = ws;                    // [32768][512]
  float* hs1 = ws + 16777216;         // [32768][512]
  // head scratch aliases hs0 region; ALL of it written only AFTER the scan
  // (transpose is launched after lstm_persistent — round-2 lesson)
  float* z1    = ws;                  // [32768][128] = 16 MB
  float* z2    = ws + 4194304;        // [32768][64]  =  8 MB
  float* w1t   = ws + 6291456;        // [512][128]
  float* w2t   = w1t + 65536;         // [128][64]
  float* part1 = w2t + 8192;          // [64][128][2]
  float* part2 = part1 + 16384;       // [64][64][2]
  float* sc1   = part2 + 8192;
  float* sh1   = sc1 + 128;
  float* sc2   = sh1 + 128;
  float* sh2   = sc2 + 64;

  poison_kernel<<<1024, 256, 0, stream>>>((uint64_t*)ws, 16777216);
  lstm_persistent<<<2*NWGL, WGT, 0, stream>>>(x, wih0, whh0, bih0, bhh0,
                                              wih1, whh1, bih1, bhh1, hs0, hs1);
  transpose_kernel<<<256, 256, 0, stream>>>(w1, w2, w1t, w2t);
  mlp1_kernel<<<8192, 128, 0, stream>>>(hs1, w1t, b1, z1);
  stats_partial<128><<<64, 128, 0, stream>>>(z1, part1);
  stats_final<128><<<1, 128, 0, stream>>>(part1, g1, be1, sc1, sh1);
  mlp2_kernel<<<4096, 64, 0, stream>>>(z1, w2t, b2, sc1, sh1, z2);
  stats_partial<64><<<64, 64, 0, stream>>>(z2, part2);
  stats_final<64><<<1, 64, 0, stream>>>(part2, g2, be2, sc2, sh2);
  mlp3_kernel<<<8192, 256, 0, stream>>>(z2, w3, b3, sc2, sh2, out);
}